// Round 11
// baseline (6622.440 us; speedup 1.0000x reference)
//
#include <hip/hip_runtime.h>

#define T_STEPS 8192
#define BATCH   128
#define HID     96

typedef __fp16 h2_t __attribute__((ext_vector_type(2)));

__device__ __forceinline__ unsigned int pk2(float a, float b) {
    return __builtin_bit_cast(unsigned int, __builtin_amdgcn_cvt_pkrtz(a, b));
}
__device__ __forceinline__ float fdot2u(unsigned int w, unsigned int h, float acc) {
    return __builtin_amdgcn_fdot2(__builtin_bit_cast(h2_t, w),
                                  __builtin_bit_cast(h2_t, h), acc, false);
}
__device__ __forceinline__ float fast_sigmoid(float v) {
    return __builtin_amdgcn_rcpf(1.0f + __expf(-v));
}
__device__ __forceinline__ float fast_tanh(float v) {   // 2*sigmoid(2v)-1
    return fmaf(2.0f, __builtin_amdgcn_rcpf(1.0f + __expf(-2.0f * v)), -1.0f);
}

// AGPR pin (R0-R9 post-mortem): the VGPR-class residency fight is unwinnable --
// MachineSink re-loads loop-invariant weights every step no matter what
// (VGPR_Count 72/36/68/64/24 across rounds; R9 is L2-BW-bound at ~128 GB/s/CU).
// AGPRs are a different register class: a value DEFINED by v_accvgpr_write asm
// cannot be rematerialized from its load, and 24 AGPR + ~32 VGPR fits the
// allocator's 64-reg/8-wave target, so there is no pressure reason to spill.
#define AW(dst, src) asm volatile("v_accvgpr_write_b32 %0, %1" : "=a"(dst) : "v"(src))
// read-back + dot (volatile: must not be hoisted/CSE'd out of the loop)
#define ARD(Avar, hcomp, ACC) { unsigned int _r;                                  \
    asm volatile("v_accvgpr_read_b32 %0, %1" : "=v"(_r) : "a"(Avar));             \
    ACC = fdot2u(_r, hcomp, ACC); }

// ---------- prepack W_hh -> f16, THREAD-MAJOR: slot s = j*8 + gp*4 + q owns ----------
// gates {2gp, 2gp+1} of unit j over cols [q*24, q*24+24); 24 contiguous u32 per slot.
__global__ void prepack_kernel(const float* __restrict__ W_hh, unsigned int* __restrict__ wpk) {
    const int i = blockIdx.x * blockDim.x + threadIdx.x;
    if (i < HID * 8 * 24) {
        const int s = i / 24, w = i % 24;
        const int j = s >> 3, gp = (s >> 2) & 1, q = s & 3;
        const int gate = 2 * gp + (w >= 12);
        const int kk   = q * 24 + (w % 12) * 2;
        const float* row = W_hh + (gate * HID + j) * HID;
        wpk[i] = pk2(row[kk], row[kk + 1]);
    }
}

__global__ __launch_bounds__(832)
void lstm_seq_kernel(const float* __restrict__ x,
                     const float* __restrict__ W_ih,
                     const float* __restrict__ b_ih,
                     const float* __restrict__ b_hh,
                     const float* __restrict__ W_fc,
                     const float* __restrict__ b_fc,
                     const uint4* __restrict__ ws_u4,   // prepacked f16 W_hh
                     float* __restrict__ out)
{
    const int b   = blockIdx.x;
    const int tid = threadIdx.x;

    __shared__ __align__(16) unsigned int hq[2][48];   // h as f16, double-buffered

    if (tid < 96) ((unsigned int*)hq)[tid] = 0u;
    __syncthreads();

    if (tid < 768) {
        // ---- worker (j, gp, q): gates {2gp,2gp+1} of unit j, cols [q*24, q*24+24) ----
        const int j  = tid >> 3;
        const int gp = (tid >> 2) & 1;
        const int q  = tid & 3;

        // load this thread's 24 weight words once, park them in 24 AGPRs
        const uint4* wp = ws_u4 + tid * 6;
        const uint4 t0 = wp[0], t1 = wp[1], t2 = wp[2];
        const uint4 t3 = wp[3], t4 = wp[4], t5 = wp[5];
        unsigned int A00,A01,A02,A03,A04,A05,A06,A07,A08,A09,A10,A11;   // gate 2gp
        unsigned int B00,B01,B02,B03,B04,B05,B06,B07,B08,B09,B10,B11;   // gate 2gp+1
        AW(A00,t0.x); AW(A01,t0.y); AW(A02,t0.z); AW(A03,t0.w);
        AW(A04,t1.x); AW(A05,t1.y); AW(A06,t1.z); AW(A07,t1.w);
        AW(A08,t2.x); AW(A09,t2.y); AW(A10,t2.z); AW(A11,t2.w);
        AW(B00,t3.x); AW(B01,t3.y); AW(B02,t3.z); AW(B03,t3.w);
        AW(B04,t4.x); AW(B05,t4.y); AW(B06,t4.z); AW(B07,t4.w);
        AW(B08,t5.x); AW(B09,t5.y); AW(B10,t5.z); AW(B11,t5.w);

        const int rowA = (2 * gp) * HID + j;
        const int rowB = rowA + HID;
        const float wihA = W_ih[rowA], bsA = b_ih[rowA] + b_hh[rowA];
        const float wihB = W_ih[rowB], bsB = b_ih[rowB] + b_hh[rowB];

        float c  = 0.0f;                // replicated across the 8-lane group
        float xt = x[0 * BATCH + b];

        for (int t = 0; t < T_STEPS; ++t) {
            const int   tn    = (t + 1 < T_STEPS) ? (t + 1) : t;
            const float xnext = x[tn * BATCH + b];           // uniform prefetch

            // 24 f16 of h: 3 b128, conflict-free (4 x 48B slices, 16-lane broadcast)
            const uint4* hb = reinterpret_cast<const uint4*>(&hq[t & 1][q * 12]);
            const uint4 h0 = hb[0], h1 = hb[1], h2 = hb[2];

            float accA = (q == 0) ? fmaf(xt, wihA, bsA) : 0.0f;
            float accB = (q == 0) ? fmaf(xt, wihB, bsB) : 0.0f;

            ARD(A00, h0.x, accA) ARD(A01, h0.y, accA) ARD(A02, h0.z, accA) ARD(A03, h0.w, accA)
            ARD(A04, h1.x, accA) ARD(A05, h1.y, accA) ARD(A06, h1.z, accA) ARD(A07, h1.w, accA)
            ARD(A08, h2.x, accA) ARD(A09, h2.y, accA) ARD(A10, h2.z, accA) ARD(A11, h2.w, accA)

            ARD(B00, h0.x, accB) ARD(B01, h0.y, accB) ARD(B02, h0.z, accB) ARD(B03, h0.w, accB)
            ARD(B04, h1.x, accB) ARD(B05, h1.y, accB) ARD(B06, h1.z, accB) ARD(B07, h1.w, accB)
            ARD(B08, h2.x, accB) ARD(B09, h2.y, accB) ARD(B10, h2.z, accB) ARD(B11, h2.w, accB)

            // reduce over q (xor 1,2), then exchange with gate-pair partner (xor 4)
            float sA = accA + __shfl_xor(accA, 1); sA += __shfl_xor(sA, 2);
            float sB = accB + __shfl_xor(accB, 1); sB += __shfl_xor(sB, 2);
            const float oA = __shfl_xor(sA, 4);
            const float oB = __shfl_xor(sB, 4);

            // gp=0 lanes: sA=i sB=f oA=g oB=o ; gp=1 lanes: sA=g sB=o oA=i oB=f
            const float pi = gp ? oA : sA;
            const float pf = gp ? oB : sB;
            const float pg = gp ? sA : oA;
            const float po = gp ? sB : oB;

            const float gi = fast_sigmoid(pi);
            const float gf = fast_sigmoid(pf);
            const float gg = fast_tanh(pg);
            const float go = fast_sigmoid(po);
            c = fmaf(gf, c, gi * gg);
            const float hn = go * fast_tanh(c);

            if ((tid & 7) == 0) ((__fp16*)&hq[(t & 1) ^ 1][0])[j] = (__fp16)hn;
            __syncthreads();
            xt = xnext;
        }
    } else {
        // -------- FC wave (wave 12): out[t-1] = h_t . W_fc + b_fc + x[t-1] --------
        const int   lane = tid - 768;
        const float wfa  = W_fc[lane];
        const float wfb  = (lane < 32) ? W_fc[64 + lane] : 0.0f;
        const float bfc  = b_fc[0];

        float xfc = x[b];                                     // x[t-1] for t=1
        for (int t = 0; t < T_STEPS; ++t) {
            const float xnext = x[t * BATCH + b];
            if (t > 0) {
                const __fp16* hh = (const __fp16*)&hq[t & 1][0];   // h_t
                float s = (float)hh[lane] * wfa;
                if (lane < 32) s = fmaf((float)hh[64 + lane], wfb, s);
                #pragma unroll
                for (int d = 1; d < 64; d <<= 1) s += __shfl_xor(s, d);
                if (lane == 0) out[(t - 1) * BATCH + b] = s + bfc + xfc;
            }
            __syncthreads();
            xfc = xnext;
        }
        {   // final timestep: h_T is in hq[0] (T even)
            const __fp16* hh = (const __fp16*)&hq[T_STEPS & 1][0];
            float s = (float)hh[lane] * wfa;
            if (lane < 32) s = fmaf((float)hh[64 + lane], wfb, s);
            #pragma unroll
            for (int d = 1; d < 64; d <<= 1) s += __shfl_xor(s, d);
            if (lane == 0) out[(T_STEPS - 1) * BATCH + b] = s + bfc + xfc;
        }
    }
}

extern "C" void kernel_launch(void* const* d_in, const int* in_sizes, int n_in,
                              void* d_out, int out_size, void* d_ws, size_t ws_size,
                              hipStream_t stream) {
    (void)in_sizes; (void)n_in; (void)out_size; (void)ws_size;
    const float* x    = (const float*)d_in[0];
    const float* W_ih = (const float*)d_in[1];
    const float* W_hh = (const float*)d_in[2];
    const float* b_ih = (const float*)d_in[3];
    const float* b_hh = (const float*)d_in[4];
    const float* W_fc = (const float*)d_in[5];
    const float* b_fc = (const float*)d_in[6];
    float* out = (float*)d_out;
    unsigned int* wpk = (unsigned int*)d_ws;       // 96*8*24 u32 = 73728 B

    const int npack = HID * 8 * 24;
    prepack_kernel<<<dim3((npack + 255) / 256), dim3(256), 0, stream>>>(W_hh, wpk);

    lstm_seq_kernel<<<dim3(BATCH), dim3(832), 0, stream>>>(
        x, W_ih, b_ih, b_hh, W_fc, b_fc, (const uint4*)wpk, out);
}